// Round 17
// baseline (1091.027 us; speedup 1.0000x reference)
//
#include <hip/hip_runtime.h>
#include <hip/hip_bf16.h>
#include <stdint.h>

#define M_DIM 8192   // 4*2048
#define N_DIM 4096   // OUT_FEATURES
#define K_DIM 4096   // IN_FEATURES

typedef __attribute__((ext_vector_type(4))) float f32x4;
typedef __attribute__((ext_vector_type(4))) int   i32x4;

#define GLD_LDS16(gaddr, laddr)                                            \
  __builtin_amdgcn_global_load_lds(                                        \
      (const __attribute__((address_space(1))) uint32_t*)(gaddr),          \
      (__attribute__((address_space(3))) uint32_t*)(laddr), 16, 0, 0)

// ---------------------------------------------------------------------------
// i8 subtile-major layout (Xq: 32 panels, Wq: 16 panels; panel = 256 rows):
//  t = k>>6 (64 K-tiles); rp = row>>8; h = (row>>7)&1; f = (row>>4)&7;
//  lane slot l = (row&15) + ((k>>4)&3)*16 ; byte-in-slot = k&15
//  byte = (rp*64 + t)*16384 + h*8192 + f*1024 + l*16 + (k&15)
// Half-tile (128 rows x 64 k) = 8KB contiguous = one 512-thread gld_lds.
// MFMA i8 16x16x64 fragment: lane l holds row=l&15, k=(l>>4)*16..+15 (16B).
// ---------------------------------------------------------------------------

// Merged prep: blocks [0,2048): dequant W -> i8 subtile-major + sw scales;
//              blocks [2048,10240): per-row x quant -> i8 subtile-major + sxd.
__global__ __launch_bounds__(256) void prep_kernel(
    const int* __restrict__ q, const float* __restrict__ lut,
    signed char* __restrict__ Wq, float* __restrict__ sw,
    const float* __restrict__ x, signed char* __restrict__ Xq,
    float* __restrict__ sxd) {
  __shared__ char sm[16384];
  const int b = blockIdx.x;
  const int tid = threadIdx.x;
  if (b < 2048) {
    // ---- W: block covers 32 o-rows (ob) x 8 words (wb) = k 256 (4 K-tiles)
    const int ob = b >> 4, wb = b & 15;
    const int o_l = tid >> 3, w_l = tid & 7;
    const int o = ob * 32 + o_l;
    const int PLANE = N_DIM * (K_DIM / 32);
    const int base = o * (K_DIM / 32) + wb * 8 + w_l;
    uint32_t q0 = (uint32_t)q[base];
    uint32_t q1 = (uint32_t)q[PLANE + base];
    uint32_t q2 = (uint32_t)q[2 * PLANE + base];
    uint32_t q3 = (uint32_t)q[3 * PLANE + base];
    const float* lrow = lut + o * 16;
    float lmax = 1e-30f;
#pragma unroll
    for (int j = 0; j < 16; ++j) lmax = fmaxf(lmax, fabsf(lrow[j]));
    const float qs = 127.0f / lmax;
    signed char l8[16];
#pragma unroll
    for (int j = 0; j < 16; ++j)
      l8[j] = (signed char)(int)rintf(lrow[j] * qs);
    if (wb == 0 && w_l == 0) sw[o] = lmax * (1.0f / 127.0f);

    union { i32x4 v; signed char c[16]; } u0, u1;
#pragma unroll
    for (int i = 0; i < 16; ++i) {
      uint32_t idx = ((q0 >> i) & 1u) | (((q1 >> i) & 1u) << 1) |
                     (((q2 >> i) & 1u) << 2) | (((q3 >> i) & 1u) << 3);
      u0.c[i] = l8[idx];
    }
#pragma unroll
    for (int i = 16; i < 32; ++i) {
      uint32_t idx = ((q0 >> i) & 1u) | (((q1 >> i) & 1u) << 1) |
                     (((q2 >> i) & 1u) << 2) | (((q3 >> i) & 1u) << 3);
      u1.c[i - 16] = l8[idx];
    }
    const int t_local = w_l >> 1;            // 0..3
    const int f_local = o_l >> 4;            // 0..1
    const int kc0 = (w_l & 1) * 2;           // 0 or 2
    char* sp = sm + t_local * 2048 + f_local * 1024;
    *(i32x4*)(sp + ((o_l & 15) + kc0 * 16) * 16)       = u0.v;
    *(i32x4*)(sp + ((o_l & 15) + (kc0 + 1) * 16) * 16) = u1.v;
    __syncthreads();
    const int rp = ob >> 3, h = (ob >> 2) & 1, f0 = (ob * 2) & 7;
#pragma unroll
    for (int c = 0; c < 2; ++c) {
      const int ci = c * 256 + tid;          // 0..511 slots of 16B
      const int t_loc = ci >> 7, off = ci & 127;
      const size_t outb = (size_t)(rp * 64 + wb * 4 + t_loc) * 16384
                          + h * 8192 + f0 * 1024 + off * 16;
      *(i32x4*)(Wq + outb) = *(i32x4*)(sm + t_loc * 2048 + off * 16);
    }
  } else {
    // ---- x: one block per row; single read, row-max, quantize, write
    const int r = b - 2048;
    const float* xr = x + (size_t)r * K_DIM;
    float v[16];
#pragma unroll
    for (int s = 0; s < 4; ++s) {
      f32x4 u = *(const f32x4*)(xr + tid * 4 + s * 1024);
      v[s * 4 + 0] = u[0]; v[s * 4 + 1] = u[1];
      v[s * 4 + 2] = u[2]; v[s * 4 + 3] = u[3];
    }
    float m = 0.0f;
#pragma unroll
    for (int i = 0; i < 16; ++i) m = fmaxf(m, fabsf(v[i]));
#pragma unroll
    for (int off = 32; off; off >>= 1) m = fmaxf(m, __shfl_down(m, off));
    float* red = (float*)(sm + 8192);
    if ((tid & 63) == 0) red[tid >> 6] = m;
    __syncthreads();
    float rmax = fmaxf(fmaxf(red[0], red[1]), fmaxf(red[2], red[3]));
    rmax = fmaxf(rmax, 1e-30f);
    if (tid == 0) sxd[r] = rmax * (1.0f / 127.0f);
    const float qs = 127.0f / rmax;
#pragma unroll
    for (int s = 0; s < 4; ++s) {
      int qi[4];
#pragma unroll
      for (int j = 0; j < 4; ++j) {
        float qc = fminf(127.0f, fmaxf(-127.0f, rintf(v[s * 4 + j] * qs)));
        qi[j] = (int)qc;
      }
      uint32_t w = (qi[0] & 255) | ((qi[1] & 255) << 8) |
                   ((qi[2] & 255) << 16) | ((uint32_t)(qi[3] & 255) << 24);
      *(uint32_t*)(sm + tid * 4 + s * 1024) = w;
    }
    __syncthreads();
    const int rp = r >> 8, h = (r >> 7) & 1, f = (r >> 4) & 7;
    const int kt = tid >> 2, kc = tid & 3;
    const size_t outb = (size_t)(rp * 64 + kt) * 16384 + h * 8192
                        + f * 1024 + ((r & 15) + kc * 16) * 16;
    *(i32x4*)(Xq + outb) = *(i32x4*)(sm + tid * 16);
  }
}

// ---------------------------------------------------------------------------
// 256x256 i8 GEMM, R17 = R16 frozen + __launch_bounds__(512,4):
// VGPR already 124 <= 128 -> no spill; LDS 64 KiB -> 2 blocks/CU co-resident.
// Inter-block overlap fills barrier/cert stalls (the structural idle of
// R2-R16's single-block residency).
//  P1(t): stage A0,B0(t+2); read a1(t); MMA(0,0)+(0,1); lgkm0 VMC(2) bar
//  P2(t): stage A1,B1(t+2); read a0(t+1)|MMA(1,1)|b1(t+1)|MMA(1,0)|b0(t+1);
//         lgkm0 bar
// Epilogue: y = (float)acc_i32 * sxd[row]*sw[col] + bias[col].
// ---------------------------------------------------------------------------
__global__ __launch_bounds__(512, 4) void anyprec_gemm_kernel(
    const signed char* __restrict__ A,   // Xq subtile-major
    const signed char* __restrict__ B,   // Wq subtile-major
    const float* __restrict__ sxd, const float* __restrict__ sw,
    const float* __restrict__ bias,
    float* __restrict__ C) {
  __shared__ char lds[2][2][2][8192];   // [buf][mat][half][8KB] = 64 KiB

  int bid = blockIdx.x;
  int swz = (bid & 7) * 64 + (bid >> 3);
  int mb = swz >> 4;    // 32 m-tiles
  int nb = swz & 15;    // 16 n-tiles

  const int tid  = threadIdx.x;
  const int lane = tid & 63;
  const int wid  = tid >> 6;
  const int wr   = wid >> 2;   // 0..1
  const int wc   = wid & 3;    // 0..3
  const int tid16  = tid * 16;
  const int lane16 = lane * 16;

  const char* gA = (const char*)A + (size_t)mb * 1048576;  // 64 tiles * 16KB
  const char* gB = (const char*)B + (size_t)nb * 1048576;

  i32x4 acc[2][2][4][2];
#pragma unroll
  for (int qm = 0; qm < 2; ++qm)
#pragma unroll
    for (int qn = 0; qn < 2; ++qn)
#pragma unroll
      for (int mf = 0; mf < 4; ++mf)
#pragma unroll
        for (int nf = 0; nf < 2; ++nf) acc[qm][qn][mf][nf] = (i32x4)0;

  i32x4 a0[4], a1[4], b0[2], b1[2];

#define STAGE(mat, h, buf, t) {                                            \
    char* lb_ = (char*)&lds[buf][mat][h][0] + tid16;                       \
    const char* gb_ = (mat ? gB : gA) + (size_t)(t) * 16384                \
                      + (h) * 8192 + tid16;                                \
    GLD_LDS16(gb_, lb_); }

#define LDA(dst, qm, buf) {                                                \
    const char* p_ = (const char*)&lds[buf][0][qm][0] + wr * 4096          \
                     + lane16;                                             \
    _Pragma("unroll")                                                      \
    for (int mf = 0; mf < 4; ++mf)                                         \
      dst[mf] = *(const i32x4*)(p_ + mf * 1024); }

#define LDB(dst, qn, buf) {                                                \
    const char* p_ = (const char*)&lds[buf][1][qn][0] + wc * 2048          \
                     + lane16;                                             \
    _Pragma("unroll")                                                      \
    for (int nf = 0; nf < 2; ++nf)                                         \
      dst[nf] = *(const i32x4*)(p_ + nf * 1024); }

#define MMA(qm, qn, aa, bb) {                                              \
    _Pragma("unroll")                                                      \
    for (int mf = 0; mf < 4; ++mf)                                         \
      _Pragma("unroll")                                                    \
      for (int nf = 0; nf < 2; ++nf)                                       \
        acc[qm][qn][mf][nf] = __builtin_amdgcn_mfma_i32_16x16x64_i8(       \
            aa[mf], bb[nf], acc[qm][qn][mf][nf], 0, 0, 0); }

#define PRIO1 __builtin_amdgcn_s_setprio(1);
#define PRIO0 __builtin_amdgcn_s_setprio(0);
#define BAR   __builtin_amdgcn_s_barrier();
#define LGKM0 asm volatile("s_waitcnt lgkmcnt(0)" ::: "memory");
#define VMC(n) asm volatile("s_waitcnt vmcnt(" #n ")" ::: "memory");

  // ---- prologue: stage tiles 0 (buf0) and 1 (buf1); cert tile0; preload
  STAGE(0, 0, 0, 0); STAGE(1, 0, 0, 0);   // A0,B0(0)
  STAGE(0, 1, 0, 0); STAGE(1, 1, 0, 0);   // A1,B1(0)
  STAGE(0, 0, 1, 1); STAGE(1, 0, 1, 1);   // A0,B0(1)
  STAGE(0, 1, 1, 1); STAGE(1, 1, 1, 1);   // A1,B1(1)
  VMC(4); BAR;                            // tile0 certified collectively
  LDA(a0, 0, 0); LDB(b0, 0, 0); LDB(b1, 1, 0);
  LGKM0; BAR;   // preload drained before P1(0)'s A0(2) stage overwrites

  // ---- main loop: t = 0..61, buf c=t&1, n=(t+1)&1; stages target t+2
  for (int t = 0; t < 62; ++t) {
    const int c = t & 1, n = (t + 1) & 1;
    // P1(t)
    STAGE(0, 0, c, t + 2); STAGE(1, 0, c, t + 2);   // A0,B0(t+2)
    PRIO1; LDA(a1, 1, c); MMA(0, 0, a0, b0); MMA(0, 1, a0, b1); PRIO0;
    LGKM0; VMC(2); BAR;                   // tile t+1 certified collectively
    // P2(t)
    STAGE(0, 1, c, t + 2); STAGE(1, 1, c, t + 2);   // A1,B1(t+2)
    PRIO1; LDA(a0, 0, n); MMA(1, 1, a1, b1); LDB(b1, 1, n);
    MMA(1, 0, a1, b0); LDB(b0, 0, n); PRIO0;
    LGKM0; BAR;
  }

  // ---- tail: t = 62 (buf0), t = 63 (buf1); outstanding = tile63's 4 loads
  // P1(62)
  PRIO1; LDA(a1, 1, 0); MMA(0, 0, a0, b0); MMA(0, 1, a0, b1); PRIO0;
  LGKM0; VMC(0); BAR;                     // tile 63 fully certified
  // P2(62)
  PRIO1; LDA(a0, 0, 1); MMA(1, 1, a1, b1); LDB(b1, 1, 1);
  MMA(1, 0, a1, b0); LDB(b0, 0, 1); PRIO0;
  LGKM0; BAR;
  // t = 63
  PRIO1; LDA(a1, 1, 1); MMA(0, 0, a0, b0); MMA(0, 1, a0, b1);
  MMA(1, 1, a1, b1); MMA(1, 0, a1, b0); PRIO0;

  // ---- epilogue: C/D layout col=lane&15, row=(lane>>4)*4+j (dtype-indep)
  const int cL = lane & 15;
  const int rL = (lane >> 4) * 4;
#pragma unroll
  for (int qn = 0; qn < 2; ++qn)
#pragma unroll
    for (int nf = 0; nf < 2; ++nf) {
      int col = nb * 256 + qn * 128 + wc * 32 + nf * 16 + cL;
      float bv  = bias[col];
      float swc = sw[col];
#pragma unroll
      for (int qm = 0; qm < 2; ++qm)
#pragma unroll
        for (int mf = 0; mf < 4; ++mf) {
          int row0 = mb * 256 + qm * 128 + wr * 64 + mf * 16 + rL;
#pragma unroll
          for (int j = 0; j < 4; ++j) {
            int row = row0 + j;
            float s = sxd[row] * swc;
            C[(size_t)row * N_DIM + col] =
                fmaf((float)acc[qm][qn][mf][nf][j], s, bv);
          }
        }
    }
#undef STAGE
#undef LDA
#undef LDB
#undef MMA
#undef PRIO1
#undef PRIO0
#undef BAR
#undef LGKM0
#undef VMC
}

extern "C" void kernel_launch(void* const* d_in, const int* in_sizes, int n_in,
                              void* d_out, int out_size, void* d_ws, size_t ws_size,
                              hipStream_t stream) {
  const float* x    = (const float*)d_in[0];
  const int*   qw   = (const int*)d_in[1];
  const float* lut  = (const float*)d_in[2];
  const float* bias = (const float*)d_in[3];

  char* wsb = (char*)d_ws;
  signed char* Wq  = (signed char*)wsb;                         // 16 MB
  signed char* Xq  = (signed char*)(wsb + (size_t)16 * 1024 * 1024);  // 32 MB
  float*       sxd = (float*)(wsb + (size_t)48 * 1024 * 1024);  // 32 KB
  float*       sw  = sxd + M_DIM;                               // 16 KB

  {
    // 2048 W-blocks + 8192 x-row blocks, one launch (independent ranges)
    prep_kernel<<<10240, 256, 0, stream>>>(qw, lut, Wq, sw, x, Xq, sxd);
  }
  {
    dim3 grid((M_DIM / 256) * (N_DIM / 256));  // 32*16 = 512, 2 blocks/CU
    anyprec_gemm_kernel<<<grid, 512, 0, stream>>>(Xq, Wq, sxd, sw, bias,
                                                  (float*)d_out);
  }
}

// Round 18
// 190.651 us; speedup vs baseline: 5.7226x; 5.7226x over previous
//
#include <hip/hip_runtime.h>
#include <hip/hip_bf16.h>
#include <stdint.h>

#define M_DIM 8192   // 4*2048
#define N_DIM 4096   // OUT_FEATURES
#define K_DIM 4096   // IN_FEATURES

typedef __attribute__((ext_vector_type(4))) float f32x4;
typedef __attribute__((ext_vector_type(4))) int   i32x4;

#define GLD_LDS16(gaddr, laddr)                                            \
  __builtin_amdgcn_global_load_lds(                                        \
      (const __attribute__((address_space(1))) uint32_t*)(gaddr),          \
      (__attribute__((address_space(3))) uint32_t*)(laddr), 16, 0, 0)

// ---------------------------------------------------------------------------
// i8 subtile-major layout, BK=128 (Xq: 32 panels, Wq: 16 panels; panel=256r):
//  t = k>>7 (32 K-tiles); rp = row>>8; h = (row>>7)&1; f = (row>>4)&7;
//  ks = (k>>6)&1; lane slot l = (row&15) + ((k>>4)&3)*16; byte-in-slot k&15
//  byte = (rp*32 + t)*32768 + h*16384 + (f*2+ks)*1024 + l*16 + (k&15)
// Half-tile (128 rows x 128 k) = 16KB contiguous = two 512-thread gld_lds.
// MFMA i8 16x16x64 fragment: lane l holds row=l&15, k=(l>>4)*16..+15 (16B).
// ---------------------------------------------------------------------------

// Merged prep: blocks [0,2048): dequant W -> i8 subtile-major + sw scales;
//              blocks [2048,10240): per-row x quant -> i8 subtile-major + sxd.
__global__ __launch_bounds__(256) void prep_kernel(
    const int* __restrict__ q, const float* __restrict__ lut,
    signed char* __restrict__ Wq, float* __restrict__ sw,
    const float* __restrict__ x, signed char* __restrict__ Xq,
    float* __restrict__ sxd) {
  __shared__ char sm[16384];
  const int b = blockIdx.x;
  const int tid = threadIdx.x;
  if (b < 2048) {
    // ---- W: block covers 32 o-rows (ob) x 8 words (wb) = k 256 (2 K-tiles)
    const int ob = b >> 4, wb = b & 15;
    const int o_l = tid >> 3, w_l = tid & 7;
    const int o = ob * 32 + o_l;
    const int PLANE = N_DIM * (K_DIM / 32);
    const int base = o * (K_DIM / 32) + wb * 8 + w_l;
    uint32_t q0 = (uint32_t)q[base];
    uint32_t q1 = (uint32_t)q[PLANE + base];
    uint32_t q2 = (uint32_t)q[2 * PLANE + base];
    uint32_t q3 = (uint32_t)q[3 * PLANE + base];
    const float* lrow = lut + o * 16;
    float lmax = 1e-30f;
#pragma unroll
    for (int j = 0; j < 16; ++j) lmax = fmaxf(lmax, fabsf(lrow[j]));
    const float qs = 127.0f / lmax;
    signed char l8[16];
#pragma unroll
    for (int j = 0; j < 16; ++j)
      l8[j] = (signed char)(int)rintf(lrow[j] * qs);
    if (wb == 0 && w_l == 0) sw[o] = lmax * (1.0f / 127.0f);

    // word w_l covers k = (wb*8+w_l)*32 .. +31:
    //  t_loc = w_l>>2, ks = (w_l>>1)&1, kgrp = (w_l&1)*2 + chunk
    union { i32x4 v; signed char c[16]; } u0, u1;
#pragma unroll
    for (int i = 0; i < 16; ++i) {
      uint32_t idx = ((q0 >> i) & 1u) | (((q1 >> i) & 1u) << 1) |
                     (((q2 >> i) & 1u) << 2) | (((q3 >> i) & 1u) << 3);
      u0.c[i] = l8[idx];
    }
#pragma unroll
    for (int i = 16; i < 32; ++i) {
      uint32_t idx = ((q0 >> i) & 1u) | (((q1 >> i) & 1u) << 1) |
                     (((q2 >> i) & 1u) << 2) | (((q3 >> i) & 1u) << 3);
      u1.c[i - 16] = l8[idx];
    }
    const int t_loc = w_l >> 2, ks = (w_l >> 1) & 1;
    const int f_loc = o_l >> 4;              // 0..1
    const int kg0 = (w_l & 1) * 2;
    char* sp = sm + t_loc * 4096 + f_loc * 2048 + ks * 1024;
    *(i32x4*)(sp + (((o_l & 15) + kg0 * 16)) * 16)       = u0.v;
    *(i32x4*)(sp + (((o_l & 15) + (kg0 + 1) * 16)) * 16) = u1.v;
    __syncthreads();
    // sm chunk ci: t_loc=ci>>8, f_loc=(ci>>7)&1, ks=(ci>>6)&1, l=ci&63
    const int rp = ob >> 3, h = (ob >> 2) & 1;
#pragma unroll
    for (int c = 0; c < 2; ++c) {
      const int ci = c * 256 + tid;
      const int tl = ci >> 8, fl = (ci >> 7) & 1, ks2 = (ci >> 6) & 1,
                l2 = ci & 63;
      const int f = (ob * 2 + fl) & 7;
      const size_t outb = (size_t)(rp * 32 + wb * 2 + tl) * 32768
                          + h * 16384 + (f * 2 + ks2) * 1024 + l2 * 16;
      *(i32x4*)(Wq + outb) = *(i32x4*)(sm + ci * 16);
    }
  } else {
    // ---- x: one block per row; single read, row-max, quantize, write
    const int r = b - 2048;
    const float* xr = x + (size_t)r * K_DIM;
    float v[16];
#pragma unroll
    for (int s = 0; s < 4; ++s) {
      f32x4 u = *(const f32x4*)(xr + tid * 4 + s * 1024);
      v[s * 4 + 0] = u[0]; v[s * 4 + 1] = u[1];
      v[s * 4 + 2] = u[2]; v[s * 4 + 3] = u[3];
    }
    float m = 0.0f;
#pragma unroll
    for (int i = 0; i < 16; ++i) m = fmaxf(m, fabsf(v[i]));
#pragma unroll
    for (int off = 32; off; off >>= 1) m = fmaxf(m, __shfl_down(m, off));
    float* red = (float*)(sm + 8192);
    if ((tid & 63) == 0) red[tid >> 6] = m;
    __syncthreads();
    float rmax = fmaxf(fmaxf(red[0], red[1]), fmaxf(red[2], red[3]));
    rmax = fmaxf(rmax, 1e-30f);
    if (tid == 0) sxd[r] = rmax * (1.0f / 127.0f);
    const float qs = 127.0f / rmax;
#pragma unroll
    for (int s = 0; s < 4; ++s) {
      int qi[4];
#pragma unroll
      for (int j = 0; j < 4; ++j) {
        float qc = fminf(127.0f, fmaxf(-127.0f, rintf(v[s * 4 + j] * qs)));
        qi[j] = (int)qc;
      }
      uint32_t w = (qi[0] & 255) | ((qi[1] & 255) << 8) |
                   ((qi[2] & 255) << 16) | ((uint32_t)(qi[3] & 255) << 24);
      *(uint32_t*)(sm + tid * 4 + s * 1024) = w;   // sm[k] = q(x[k]) linear
    }
    __syncthreads();
    // chunk tid: k = tid*16..+15: t=tid>>3, ks=(tid>>2)&1, kgrp=tid&3
    const int rp = r >> 8, h = (r >> 7) & 1, f = (r >> 4) & 7;
    const int t = tid >> 3, ks = (tid >> 2) & 1;
    const int l = (r & 15) + (tid & 3) * 16;
    const size_t outb = (size_t)(rp * 32 + t) * 32768 + h * 16384
                        + (f * 2 + ks) * 1024 + l * 16;
    *(i32x4*)(Xq + outb) = *(i32x4*)(sm + tid * 16);
  }
}

// ---------------------------------------------------------------------------
// 256x256 i8 GEMM, R18: m201 8-PHASE TEMPLATE ported to i8 BK=128.
// 8 waves (2M x 4N), per-wave 128x64, 16 MFMA/phase (one C-quadrant x K=128).
// LDS 128 KiB = [buf][A/B][half][16KB]. Per phase: {reads | 1 half-tile
// stage} bar lgkm0 prio1 16xMFMA prio0 bar. vmcnt(6) ONLY at ph4/ph8
// (3 half-tiles in flight; each cert drains exactly one tile, all halves
// staged >=3 phases earlier). Read balance 12/4/8/0 per 4-phase group.
// Stage rotation: ph1=A1(O) ph2=A0(E+2) ph3=B0(E+2) ph4=B1(E+2)
//                 ph5=A1(E+2) ph6=A0(O+2) ph7=B0(O+2) ph8=B1(O+2)
// ---------------------------------------------------------------------------
__global__ __launch_bounds__(512, 2) void anyprec_gemm_kernel(
    const signed char* __restrict__ A,   // Xq subtile-major
    const signed char* __restrict__ B,   // Wq subtile-major
    const float* __restrict__ sxd, const float* __restrict__ sw,
    const float* __restrict__ bias,
    float* __restrict__ C) {
  __shared__ char lds[2][2][2][16384];   // [buf][mat][half][16KB] = 128 KiB

  int bid = blockIdx.x;
  int swz = (bid & 7) * 64 + (bid >> 3);
  int mb = swz >> 4;    // 32 m-tiles
  int nb = swz & 15;    // 16 n-tiles

  const int tid  = threadIdx.x;
  const int lane = tid & 63;
  const int wid  = tid >> 6;
  const int wr   = wid >> 2;   // 0..1
  const int wc   = wid & 3;    // 0..3
  const int tid16  = tid * 16;
  const int lane16 = lane * 16;

  const char* gA = (const char*)A + (size_t)mb * 1048576;  // 32 tiles * 32KB
  const char* gB = (const char*)B + (size_t)nb * 1048576;

  i32x4 acc[2][2][4][2];
#pragma unroll
  for (int qm = 0; qm < 2; ++qm)
#pragma unroll
    for (int qn = 0; qn < 2; ++qn)
#pragma unroll
      for (int mf = 0; mf < 4; ++mf)
#pragma unroll
        for (int nf = 0; nf < 2; ++nf) acc[qm][qn][mf][nf] = (i32x4)0;

  i32x4 a0[4][2], a1[4][2], b0[2][2], b1[2][2];

#define STAGE(mat, h, buf, t) {                                            \
    char* lb_ = (char*)&lds[buf][mat][h][0] + tid16;                       \
    const char* gb_ = (mat ? gB : gA) + (size_t)(t) * 32768                \
                      + (h) * 16384 + tid16;                               \
    GLD_LDS16(gb_,        lb_);                                            \
    GLD_LDS16(gb_ + 8192, lb_ + 8192); }

#define LDA(dst, qm, buf) {                                                \
    const char* p_ = (const char*)&lds[buf][0][qm][0] + wr * 8192          \
                     + lane16;                                             \
    _Pragma("unroll")                                                      \
    for (int mf = 0; mf < 4; ++mf)                                         \
      _Pragma("unroll")                                                    \
      for (int ks = 0; ks < 2; ++ks)                                       \
        dst[mf][ks] = *(const i32x4*)(p_ + mf * 2048 + ks * 1024); }

#define LDB(dst, qn, buf) {                                                \
    const char* p_ = (const char*)&lds[buf][1][qn][0] + wc * 4096          \
                     + lane16;                                             \
    _Pragma("unroll")                                                      \
    for (int nf = 0; nf < 2; ++nf)                                         \
      _Pragma("unroll")                                                    \
      for (int ks = 0; ks < 2; ++ks)                                       \
        dst[nf][ks] = *(const i32x4*)(p_ + nf * 2048 + ks * 1024); }

#define MMA(qm, qn, aa, bb) {                                              \
    _Pragma("unroll")                                                      \
    for (int mf = 0; mf < 4; ++mf)                                         \
      _Pragma("unroll")                                                    \
      for (int nf = 0; nf < 2; ++nf) {                                     \
        acc[qm][qn][mf][nf] = __builtin_amdgcn_mfma_i32_16x16x64_i8(       \
            aa[mf][0], bb[nf][0], acc[qm][qn][mf][nf], 0, 0, 0);           \
        acc[qm][qn][mf][nf] = __builtin_amdgcn_mfma_i32_16x16x64_i8(       \
            aa[mf][1], bb[nf][1], acc[qm][qn][mf][nf], 0, 0, 0); } }

#define PRIO1 __builtin_amdgcn_s_setprio(1);
#define PRIO0 __builtin_amdgcn_s_setprio(0);
#define BAR   __builtin_amdgcn_s_barrier();
#define LGKM0 asm volatile("s_waitcnt lgkmcnt(0)" ::: "memory");
#define LGKM8 asm volatile("s_waitcnt lgkmcnt(8)" ::: "memory");
#define VMC(n) asm volatile("s_waitcnt vmcnt(" #n ")" ::: "memory");

  // ---- prologue: tile0 (4 halves) + A0,B0,B1(1); cert tile0 (drain 8 of 14)
  STAGE(0, 0, 0, 0); STAGE(1, 0, 0, 0);   // A0,B0(0)
  STAGE(0, 1, 0, 0); STAGE(1, 1, 0, 0);   // A1,B1(0)
  STAGE(0, 0, 1, 1); STAGE(1, 0, 1, 1);   // A0,B0(1)
  STAGE(1, 1, 1, 1);                      // B1(1)
  VMC(6); BAR;                            // tile0 certified collectively

  // ---- main loop: i = 0..14, tiles E=2i (buf0), O=2i+1 (buf1)
  for (int i = 0; i < 15; ++i) {
    const int O = 2 * i + 1, E2 = 2 * i + 2, O2 = 2 * i + 3;
    // ph1: reads a0,b0(E) [12]; stage A1(O)
    LDA(a0, 0, 0); LDB(b0, 0, 0); STAGE(0, 1, 1, O);
    LGKM8; BAR; LGKM0;
    PRIO1; MMA(0, 0, a0, b0); PRIO0; BAR;
    // ph2: reads b1(E) [4]; stage A0(E+2)
    LDB(b1, 1, 0); STAGE(0, 0, 0, E2);
    BAR; LGKM0;
    PRIO1; MMA(0, 1, a0, b1); PRIO0; BAR;
    // ph3: reads a1(E) [8]; stage B0(E+2)
    LDA(a1, 1, 0); STAGE(1, 0, 0, E2);
    BAR; LGKM0;
    PRIO1; MMA(1, 1, a1, b1); PRIO0; BAR;
    // ph4: no reads; stage B1(E+2); CERT tile O (vmcnt(6) pre-barrier)
    STAGE(1, 1, 0, E2);
    BAR;
    PRIO1; MMA(1, 0, a1, b0); PRIO0; VMC(6); BAR;
    // ph5: reads a0,b0(O) [12]; stage A1(E+2)
    LDA(a0, 0, 1); LDB(b0, 0, 1); STAGE(0, 1, 0, E2);
    LGKM8; BAR; LGKM0;
    PRIO1; MMA(0, 0, a0, b0); PRIO0; BAR;
    // ph6: reads b1(O) [4]; stage A0(O+2)
    LDB(b1, 1, 1); STAGE(0, 0, 1, O2);
    BAR; LGKM0;
    PRIO1; MMA(0, 1, a0, b1); PRIO0; BAR;
    // ph7: reads a1(O) [8]; stage B0(O+2)
    LDA(a1, 1, 1); STAGE(1, 0, 1, O2);
    BAR; LGKM0;
    PRIO1; MMA(1, 1, a1, b1); PRIO0; BAR;
    // ph8: no reads; stage B1(O+2); CERT tile E+2
    STAGE(1, 1, 1, O2);
    BAR;
    PRIO1; MMA(1, 0, a1, b0); PRIO0; VMC(6); BAR;
  }

  // ---- tail: tiles 30 (buf0), 31 (buf1); outstanding: A0,B0,B1(31)
  // T-ph1: reads a0,b0(30); stage A1(31)
  LDA(a0, 0, 0); LDB(b0, 0, 0); STAGE(0, 1, 1, 31);
  LGKM8; BAR; LGKM0;
  PRIO1; MMA(0, 0, a0, b0); PRIO0; BAR;
  // T-ph2
  LDB(b1, 1, 0);
  BAR; LGKM0;
  PRIO1; MMA(0, 1, a0, b1); PRIO0; BAR;
  // T-ph3
  LDA(a1, 1, 0);
  BAR; LGKM0;
  PRIO1; MMA(1, 1, a1, b1); PRIO0; BAR;
  // T-ph4: CERT tile 31 fully
  BAR;
  PRIO1; MMA(1, 0, a1, b0); PRIO0; VMC(0); BAR;
  // T-ph5
  LDA(a0, 0, 1); LDB(b0, 0, 1);
  LGKM8; BAR; LGKM0;
  PRIO1; MMA(0, 0, a0, b0); PRIO0; BAR;
  // T-ph6
  LDB(b1, 1, 1);
  BAR; LGKM0;
  PRIO1; MMA(0, 1, a0, b1); PRIO0; BAR;
  // T-ph7
  LDA(a1, 1, 1);
  BAR; LGKM0;
  PRIO1; MMA(1, 1, a1, b1); PRIO0;
  // T-ph8
  MMA(1, 0, a1, b0);

  // ---- epilogue: C/D layout col=lane&15, row=(lane>>4)*4+j (dtype-indep)
  const int cL = lane & 15;
  const int rL = (lane >> 4) * 4;
#pragma unroll
  for (int qn = 0; qn < 2; ++qn)
#pragma unroll
    for (int nf = 0; nf < 2; ++nf) {
      int col = nb * 256 + qn * 128 + wc * 32 + nf * 16 + cL;
      float bv  = bias[col];
      float swc = sw[col];
#pragma unroll
      for (int qm = 0; qm < 2; ++qm)
#pragma unroll
        for (int mf = 0; mf < 4; ++mf) {
          int row0 = mb * 256 + qm * 128 + wr * 64 + mf * 16 + rL;
#pragma unroll
          for (int j = 0; j < 4; ++j) {
            int row = row0 + j;
            float s = sxd[row] * swc;
            C[(size_t)row * N_DIM + col] =
                fmaf((float)acc[qm][qn][mf][nf][j], s, bv);
          }
        }
    }
#undef STAGE
#undef LDA
#undef LDB
#undef MMA
#undef PRIO1
#undef PRIO0
#undef BAR
#undef LGKM0
#undef LGKM8
#undef VMC
}

extern "C" void kernel_launch(void* const* d_in, const int* in_sizes, int n_in,
                              void* d_out, int out_size, void* d_ws, size_t ws_size,
                              hipStream_t stream) {
  const float* x    = (const float*)d_in[0];
  const int*   qw   = (const int*)d_in[1];
  const float* lut  = (const float*)d_in[2];
  const float* bias = (const float*)d_in[3];

  char* wsb = (char*)d_ws;
  signed char* Wq  = (signed char*)wsb;                         // 16 MB
  signed char* Xq  = (signed char*)(wsb + (size_t)16 * 1024 * 1024);  // 32 MB
  float*       sxd = (float*)(wsb + (size_t)48 * 1024 * 1024);  // 32 KB
  float*       sw  = sxd + M_DIM;                               // 16 KB

  {
    // 2048 W-blocks + 8192 x-row blocks, one launch (independent ranges)
    prep_kernel<<<10240, 256, 0, stream>>>(qw, lut, Wq, sw, x, Xq, sxd);
  }
  {
    dim3 grid((M_DIM / 256) * (N_DIM / 256));  // 32*16 = 512
    anyprec_gemm_kernel<<<grid, 512, 0, stream>>>(Xq, Wq, sxd, sw, bias,
                                                  (float*)d_out);
  }
}